// Round 15
// baseline (584.782 us; speedup 1.0000x reference)
//
#include <hip/hip_runtime.h>
#include <hip/hip_bf16.h>

// MoE top-2 of 8 experts. N=8192 tokens, D=1024, F=2048.
// R15: LDS-free, barrier-free fragment-direct GEMM. All operands stored in
//      MFMA-fragment-tiled layout [rowtile16][kchunk8][lane16] so every
//      fragment is ONE coalesced 256B global_load_dwordx4 from L2:
//        - xpack: gather pass writes packed token rows frag-tiled
//        - w1t/w2t: transpose pass writes B^T frag-tiled
//        - h: GEMM1 epilogue writes frag-tiled (via LDS C-tile)
//      K-loop per wave: {load 6 frags of t+1 || 8 MFMA of t} - no LDS
//      staging, no s_barrier, no vmcnt asm; 16 independent waves/CU.
//      Expert segments ceil-16 padded (aoffs); over-range rowtiles clamped
//      (their outputs are discarded; D rows depend only on A rows).
//      Persistent mt-major XCD-chunked walk + split-K2 (GEMM2) retained.

#define N_TOK 8192
#define DIM   1024
#define FF    2048
#define NE    8
#define ROWS_PAD 16512          // 1032 row-tiles of 16 (16384 + pad + margin)
#define MAXTILE  1031

typedef unsigned short ushort_t;
typedef __bf16 bf16x8 __attribute__((ext_vector_type(8)));
typedef float  f32x4  __attribute__((ext_vector_type(4)));
typedef unsigned short u16x8 __attribute__((ext_vector_type(8)));

__device__ __forceinline__ ushort_t f2bf(float f) {
    union { float f; unsigned int u; } v; v.f = f;
    unsigned int r = (v.u + 0x7FFFu + ((v.u >> 16) & 1u)) >> 16;  // RNE
    return (ushort_t)r;
}

__device__ __forceinline__ unsigned int pkbf2(float lo, float hi) {
    __hip_bfloat162 h = __float22bfloat162_rn(make_float2(lo, hi));
    return *reinterpret_cast<unsigned int*>(&h);
}

// ---------------- router: 128 blocks x 64 tokens; ballot ranking, 8 atomics/blk ----
__global__ __launch_bounds__(256) void router_kernel(
    const float* __restrict__ x, const float* __restrict__ Wr, const float* __restrict__ br,
    int* __restrict__ cnt, int* __restrict__ tok_list, float* __restrict__ w_list)
{
    __shared__ int   se0[64], se1[64];
    __shared__ float sw0[64], sw1[64];

    const int wid  = threadIdx.x >> 6;
    const int lane = threadIdx.x & 63;
    const int tblk = blockIdx.x * 64;

    for (int i = 0; i < 16; ++i) {
        const int li = wid * 16 + i;
        const int t  = tblk + li;
        const float* xr = x + (size_t)t * DIM;

        float acc[NE];
#pragma unroll
        for (int e = 0; e < NE; ++e) acc[e] = 0.f;
        for (int d = lane; d < DIM; d += 64) {
            float xv = xr[d];
            const float4* w4 = reinterpret_cast<const float4*>(Wr + (size_t)d * NE);
            float4 w0 = w4[0], w1 = w4[1];
            acc[0] += xv * w0.x; acc[1] += xv * w0.y; acc[2] += xv * w0.z; acc[3] += xv * w0.w;
            acc[4] += xv * w1.x; acc[5] += xv * w1.y; acc[6] += xv * w1.z; acc[7] += xv * w1.w;
        }
#pragma unroll
        for (int e = 0; e < NE; ++e) {
            for (int off = 32; off > 0; off >>= 1)
                acc[e] += __shfl_down(acc[e], off, 64);
        }
        if (lane == 0) {
            float l[NE];
#pragma unroll
            for (int e = 0; e < NE; ++e) l[e] = acc[e] + br[e];
            float mx = l[0];
#pragma unroll
            for (int e = 1; e < NE; ++e) mx = fmaxf(mx, l[e]);
            float p[NE], s = 0.f;
#pragma unroll
            for (int e = 0; e < NE; ++e) { p[e] = expf(l[e] - mx); s += p[e]; }
            float inv = 1.f / s;
            int e0 = 0;
#pragma unroll
            for (int e = 1; e < NE; ++e) if (l[e] > l[e0]) e0 = e;
            int e1 = (e0 == 0) ? 1 : 0;
#pragma unroll
            for (int e = 0; e < NE; ++e) if (e != e0 && l[e] > l[e1]) e1 = e;
            se0[li] = e0; sw0[li] = p[e0] * inv;
            se1[li] = e1; sw1[li] = p[e1] * inv;
        }
    }
    __syncthreads();

    if (threadIdx.x < 64) {
        const int t  = tblk + lane;
        const int e0 = se0[lane], e1 = se1[lane];
        const unsigned long long below = ((unsigned long long)1 << lane) - 1;
        int p0 = 0, p1 = 0;
#pragma unroll
        for (int e = 0; e < NE; ++e) {
            unsigned long long m0 = __ballot(e0 == e);
            unsigned long long m1 = __ballot(e1 == e);
            int c = __popcll(m0) + __popcll(m1);
            int b = 0;
            if (lane == e && c) b = atomicAdd(&cnt[e], c);
            b = __shfl(b, e, 64);
            if (e0 == e) p0 = b + __popcll(m0 & below);
            if (e1 == e) p1 = b + __popcll(m0) + __popcll(m1 & below);
        }
        tok_list[e0 * N_TOK + p0] = t;  w_list[e0 * N_TOK + p0] = sw0[lane];
        tok_list[e1 * N_TOK + p1] = t;  w_list[e1 * N_TOK + p1] = sw1[lane];
    }
}

// scan: aligned (ceil-16) packed offsets + live-tile table (128-row m-tiles)
__global__ void scan_kernel(const int* __restrict__ cnt, int* __restrict__ aoffs,
                            int* __restrict__ tile_e, int* __restrict__ tile_m0,
                            int* __restrict__ meta)
{
    if (threadIdx.x == 0 && blockIdx.x == 0) {
        int s = 0;
        for (int e = 0; e < NE; ++e) { aoffs[e] = s; s += (cnt[e] + 15) & ~15; }
        aoffs[NE] = s;
        int nt = 0;
        for (int e = 0; e < NE; ++e)
            for (int m0 = 0; m0 < cnt[e]; m0 += 128) {
                tile_e[nt] = e; tile_m0[nt] = m0; ++nt;
            }
        meta[0] = nt;
    }
}

// ---------------- gather + convert + frag-tile pack: xpack from x ----------------
// thread c: row = c>>7 (packed row), d0 = (c&127)*8. Coalesced x reads;
// frag-tiled 16B writes at [(row>>4)*128 + d0/8][row&15].
__global__ __launch_bounds__(256) void gather_pack_kernel(
    const float* __restrict__ x, const int* __restrict__ cnt,
    const int* __restrict__ aoffs, const int* __restrict__ tok_list,
    ushort_t* __restrict__ xpack)
{
    const int c   = blockIdx.x * 256 + threadIdx.x;
    const int row = c >> 7;
    const int d0  = (c & 127) << 3;
    int e = 0;
#pragma unroll
    for (int k = 1; k < NE; ++k) e += (row >= aoffs[k]);
    int entry = row - aoffs[e];
    int ce = cnt[e];
    if (entry >= ce) entry = (ce > 0) ? ce - 1 : 0;   // pad rows: any valid token
    const int tok = tok_list[e * N_TOK + entry] & (N_TOK - 1);  // clamp vs poison
    const float* src = x + ((size_t)tok << 10) + d0;
    float4 a = *reinterpret_cast<const float4*>(src);
    float4 b = *reinterpret_cast<const float4*>(src + 4);
    u16x8 o;
    o[0] = f2bf(a.x); o[1] = f2bf(a.y); o[2] = f2bf(a.z); o[3] = f2bf(a.w);
    o[4] = f2bf(b.x); o[5] = f2bf(b.y); o[6] = f2bf(b.z); o[7] = f2bf(b.w);
    size_t off = ((size_t)(row >> 4) * 128 + (d0 >> 3)) * 128 + (row & 15) * 8;
    *reinterpret_cast<u16x8*>(xpack + off) = o;
}

// ------- transpose + convert + frag-tile: in [E][R][C] f32 -> out frag-tiled B^T ----
// out layout: [C/16 coltiles][R/8 kchunks][16 lanes x 8 bf16] per expert.
__global__ __launch_bounds__(256) void transpose_pack_kernel(
    const float* __restrict__ in, ushort_t* __restrict__ out, int R, int C)
{
    __shared__ float tile[64][68];
    const int e = blockIdx.z;
    const float* I = in + (size_t)e * R * C;
    ushort_t*    O = out + (size_t)e * R * C;
    const int c0 = blockIdx.x * 64, r0 = blockIdx.y * 64;
    const int tid = threadIdx.x;
#pragma unroll
    for (int j = 0; j < 4; ++j) {
        int row = j * 16 + (tid >> 4);
        int col = (tid & 15) * 4;
        float4 v = *reinterpret_cast<const float4*>(&I[(size_t)(r0 + row) * C + c0 + col]);
        *reinterpret_cast<float4*>(&tile[row][col]) = v;
    }
    __syncthreads();
    const int la  = tid & 15;
    const int KC8 = R >> 3;
#pragma unroll
    for (int j = 0; j < 2; ++j) {
        int u = (tid >> 4) + j * 16;      // 32 units: 4 coltiles x 8 rowchunks
        int ctile = u & 3, rchunk = u >> 2;
        int col = ctile * 16 + la;        // within 64
        int rb  = rchunk * 8;
        uint4 o;
        o.x = pkbf2(tile[rb + 0][col], tile[rb + 1][col]);
        o.y = pkbf2(tile[rb + 2][col], tile[rb + 3][col]);
        o.z = pkbf2(tile[rb + 4][col], tile[rb + 5][col]);
        o.w = pkbf2(tile[rb + 6][col], tile[rb + 7][col]);
        int ctg = (c0 >> 4) + ctile;
        int chk = (r0 >> 3) + rchunk;
        *reinterpret_cast<uint4*>(&O[((size_t)ctg * KC8 + chk) * 128 + la * 8]) = o;
    }
}

// ------- fragment-direct persistent grouped GEMM: no LDS staging, no barriers -----
// 512 thr (8 waves: 2 row-halves x 4 col-quarters), per-wave 64x32 out.
// K-window = 1024 (MODE1 split-K2 via kh). nk = 32 steps of BK=32 (4 chunks).
// MODE 0: A=xpack (K=1024), B=w1t; epilogue bias+GELU -> frag-tiled h via LDS.
// MODE 1: A=h (K=2048), B=w2t; epilogue (kh==0?bias:0) * w, atomicAdd -> out.
template <int MODE>
__global__ __launch_bounds__(512, 4) void moe_gemm_kernel(
    const ushort_t* __restrict__ A,
    const ushort_t* __restrict__ Bt,
    const float*    __restrict__ bias,
    const int*      __restrict__ cnt,
    const int*      __restrict__ aoffs,
    const int*      __restrict__ tok_list,
    const float*    __restrict__ w_list,
    const int*      __restrict__ tile_e,
    const int*      __restrict__ tile_m0,
    const int*      __restrict__ meta,
    ushort_t*       __restrict__ hout,
    float*          __restrict__ out)
{
    const int K    = (MODE == 0) ? DIM : FF;
    const int NCOL = (MODE == 0) ? FF : DIM;
    const int KC8  = K >> 3;                  // chunks per row

    __shared__ ushort_t smem[(MODE == 0) ? 128 * 136 : 16];

    const int nmt = meta[0];
    const int L   = nmt << 4;                 // 16 sub-tiles per m-tile, both modes

    const int xcd = blockIdx.x & 7;
    const int q = L >> 3, r = L & 7;
    const int cstart = (xcd < r) ? xcd * (q + 1) : r * (q + 1) + (xcd - r) * q;
    const int clen   = (xcd < r) ? q + 1 : q;

    const int tid  = threadIdx.x;
    const int lane = tid & 63;
    const int wid  = tid >> 6;
    const int wr = (wid >> 2) * 64;    // wave rows [wr, wr+64)
    const int wc = (wid & 3) * 32;     // wave cols [wc, wc+32)
    const int la = lane & 15;
    const int kc = lane >> 4;          // k-chunk 0..3 within 32-k step

    for (int i = blockIdx.x >> 3; i < clen; i += 64) {
        const int tau = cstart + i;
        const int mt  = tau >> 4;
        int nb, kh;
        if (MODE == 0) { nb = tau & 15; kh = 0; }
        else           { kh = tau & 1;  nb = (tau >> 1) & 7; }
        const int e   = tile_e[mt];
        const int m0  = tile_m0[mt];
        const int cnt_e = cnt[e];
        const int am0   = aoffs[e] + m0;      // aligned packed row base (16-mult)
        const int n0  = nb * 128;

        // fragment base offsets (elements, 32-bit)
        unsigned int aB[4], bB[2];
#pragma unroll
        for (int m = 0; m < 4; ++m) {
            int rt = ((am0 + wr) >> 4) + m;
            if (rt > MAXTILE) rt = MAXTILE;   // over-range: outputs discarded
            aB[m] = ((unsigned int)rt * KC8 + (MODE == 1 ? kh * 128 : 0) + kc) * 128 + la * 8;
        }
        const ushort_t* Be = Bt + (size_t)e * NCOL * K;
#pragma unroll
        for (int n = 0; n < 2; ++n) {
            int ct = ((n0 + wc) >> 4) + n;
            bB[n] = ((unsigned int)ct * KC8 + (MODE == 1 ? kh * 128 : 0) + kc) * 128 + la * 8;
        }

        f32x4 acc[4][2];
#pragma unroll
        for (int m = 0; m < 4; ++m)
#pragma unroll
            for (int n = 0; n < 2; ++n)
                acc[m][n] = (f32x4){0.f, 0.f, 0.f, 0.f};

        auto LOADF = [&](bf16x8* ar, bf16x8* br, int t) {
            const unsigned int d = (unsigned int)t * 512u;
#pragma unroll
            for (int m = 0; m < 4; ++m)
                ar[m] = *reinterpret_cast<const bf16x8*>(A + aB[m] + d);
#pragma unroll
            for (int n = 0; n < 2; ++n)
                br[n] = *reinterpret_cast<const bf16x8*>(Be + bB[n] + d);
        };
        auto MM = [&](const bf16x8* ar, const bf16x8* br) {
            __builtin_amdgcn_s_setprio(1);
#pragma unroll
            for (int m = 0; m < 4; ++m)
#pragma unroll
                for (int n = 0; n < 2; ++n)
                    acc[m][n] = __builtin_amdgcn_mfma_f32_16x16x32_bf16(
                        ar[m], br[n], acc[m][n], 0, 0, 0);
            __builtin_amdgcn_s_setprio(0);
        };

        bf16x8 a0[4], b0[2], a1[4], b1[2];
        LOADF(a0, b0, 0);
        const int nk = 32;
        for (int t = 0; t < nk; t += 2) {
            if (t + 1 < nk) LOADF(a1, b1, t + 1);
            MM(a0, b0);
            if (t + 2 < nk) LOADF(a0, b0, t + 2);
            MM(a1, b1);
        }

        // epilogue: C/D layout col = lane&15, row = (lane>>4)*4 + j (HW-verified)
        if (MODE == 0) {
            __syncthreads();   // prev tile's smem readers done; all waves ready
#pragma unroll
            for (int m = 0; m < 4; ++m) {
                int rbase = wr + m * 16 + (lane >> 4) * 4;
#pragma unroll
                for (int n = 0; n < 2; ++n) {
                    int ccol = wc + n * 16 + la;
                    float bi = bias[(size_t)e * NCOL + n0 + ccol];
#pragma unroll
                    for (int jj = 0; jj < 4; ++jj) {
                        float v = acc[m][n][jj] + bi;
                        // gelu tanh approx: tanh(u)=(t2-1)/(t2+1), t2=exp2(2u*log2e)
                        float u = 0.7978845608028654f * (v + 0.044715f * v * v * v);
                        float t2 = __builtin_amdgcn_exp2f(2.8853900817779268f * u);
                        float g = v * (t2 / (t2 + 1.f));
                        smem[(rbase + jj) * 136 + ccol] = f2bf(g);
                    }
                }
            }
            __syncthreads();
            // frag-tiled h writes: 2048 units = 8 rowblks x 16 colgroups x 16 lanes
#pragma unroll
            for (int j = 0; j < 4; ++j) {
                int c = tid + 512 * j;
                int la2   = c & 15;
                int colc  = (c >> 4) & 15;
                int rowbk = c >> 8;
                int row   = rowbk * 16 + la2;
                int entry = m0 + row;
                if (entry < cnt_e) {
                    int gr = am0 + row;       // gr&15 == la2 (am0 16-aligned)
                    u16x8 v = *reinterpret_cast<const u16x8*>(&smem[row * 136 + colc * 8]);
                    size_t off = ((size_t)(gr >> 4) * 256 + ((n0 + colc * 8) >> 3)) * 128 + la2 * 8;
                    *reinterpret_cast<u16x8*>(hout + off) = v;
                }
            }
        } else {
#pragma unroll
            for (int m = 0; m < 4; ++m) {
                int rbase = wr + m * 16 + (lane >> 4) * 4;
#pragma unroll
                for (int n = 0; n < 2; ++n) {
                    int gcol = n0 + wc + n * 16 + la;
                    float bi = (kh != 0) ? 0.f : bias[(size_t)e * NCOL + gcol];
#pragma unroll
                    for (int jj = 0; jj < 4; ++jj) {
                        int entry = m0 + rbase + jj;
                        if (entry < cnt_e) {
                            float v = acc[m][n][jj] + bi;
                            int tok  = tok_list[e * N_TOK + entry];
                            float w  = w_list  [e * N_TOK + entry];
                            atomicAdd(&out[(size_t)tok * DIM + gcol], w * v);
                        }
                    }
                }
            }
        }
    }
}

extern "C" void kernel_launch(void* const* d_in, const int* in_sizes, int n_in,
                              void* d_out, int out_size, void* d_ws, size_t ws_size,
                              hipStream_t stream)
{
    const float* x  = (const float*)d_in[0];
    const float* Wr = (const float*)d_in[1];
    const float* br = (const float*)d_in[2];
    const float* W1 = (const float*)d_in[3];
    const float* b1 = (const float*)d_in[4];
    const float* W2 = (const float*)d_in[5];
    const float* b2 = (const float*)d_in[6];
    float* out = (float*)d_out;

    // workspace layout (~170 MB total)
    char* ws = (char*)d_ws;
    size_t off = 0;
    auto alloc = [&](size_t bytes) -> void* {
        void* p = ws + off;
        off = (off + bytes + 255) & ~(size_t)255;
        return p;
    };
    ushort_t* w1t   = (ushort_t*)alloc((size_t)NE * DIM * FF * 2);     // 32 MB frag-tiled
    ushort_t* w2t   = (ushort_t*)alloc((size_t)NE * DIM * FF * 2);     // 32 MB frag-tiled
    ushort_t* xpack = (ushort_t*)alloc((size_t)ROWS_PAD * DIM * 2);    // 33.8 MB frag-tiled
    ushort_t* h     = (ushort_t*)alloc((size_t)ROWS_PAD * FF * 2);     // 67.6 MB frag-tiled
    int*      cnt   = (int*)alloc(NE * sizeof(int));
    int*      aoffs = (int*)alloc((NE + 1) * sizeof(int));
    int*   tok_list = (int*)alloc((size_t)NE * N_TOK * sizeof(int));
    float* w_list   = (float*)alloc((size_t)NE * N_TOK * sizeof(float));
    int*   tile_e   = (int*)alloc(256 * sizeof(int));
    int*   tile_m0  = (int*)alloc(256 * sizeof(int));
    int*   meta     = (int*)alloc(16 * sizeof(int));
    (void)ws_size; (void)in_sizes; (void)n_in;

    hipMemsetAsync(out, 0, (size_t)out_size * sizeof(float), stream);
    hipMemsetAsync(cnt, 0, NE * sizeof(int), stream);

    transpose_pack_kernel<<<dim3(FF / 64, DIM / 64, NE), 256, 0, stream>>>(W1, w1t, DIM, FF);
    transpose_pack_kernel<<<dim3(DIM / 64, FF / 64, NE), 256, 0, stream>>>(W2, w2t, FF, DIM);
    router_kernel<<<N_TOK / 64, 256, 0, stream>>>(x, Wr, br, cnt, tok_list, w_list);
    scan_kernel<<<1, 64, 0, stream>>>(cnt, aoffs, tile_e, tile_m0, meta);
    gather_pack_kernel<<<(ROWS_PAD * 128) / 256, 256, 0, stream>>>(x, cnt, aoffs, tok_list, xpack);

    moe_gemm_kernel<0><<<512, 512, 0, stream>>>(
        xpack, w1t, b1, cnt, aoffs, tok_list, w_list, tile_e, tile_m0, meta, h, nullptr);
    moe_gemm_kernel<1><<<512, 512, 0, stream>>>(
        h, w2t, b2, cnt, aoffs, tok_list, w_list, tile_e, tile_m0, meta, nullptr, out);
}

// Round 17
// 477.913 us; speedup vs baseline: 1.2236x; 1.2236x over previous
//
#include <hip/hip_runtime.h>
#include <hip/hip_bf16.h>

// MoE top-2 of 8 experts. N=8192 tokens, D=1024, F=2048.
// R17: R16 with the fused-convert coverage bug fixed: each router block owns
//      64 tok x 1024 dim = 65536 elems = 8192 chunks of 8 -> j<32 (was j<8,
//      leaving 3/4 of xb as poison). GEMMs byte-identical to R14/R16
//      (persistent 128x128/BK32/8-wave, 3 LDS bufs, vmcnt(2) pipeline,
//      mt-major XCD walk, split-K2, LDS-coalesced GEMM1 epilogue).

#define N_TOK 8192
#define DIM   1024
#define FF    2048
#define NE    8

typedef unsigned short ushort_t;
typedef __bf16 bf16x8 __attribute__((ext_vector_type(8)));
typedef float  f32x4  __attribute__((ext_vector_type(4)));
typedef unsigned short u16x8 __attribute__((ext_vector_type(8)));

__device__ __forceinline__ ushort_t f2bf(float f) {
    union { float f; unsigned int u; } v; v.f = f;
    unsigned int r = (v.u + 0x7FFFu + ((v.u >> 16) & 1u)) >> 16;  // RNE
    return (ushort_t)r;
}

__device__ __forceinline__ unsigned int pkbf2(float lo, float hi) {
    __hip_bfloat162 h = __float22bfloat162_rn(make_float2(lo, hi));
    return *reinterpret_cast<unsigned int*>(&h);
}

__device__ __forceinline__ void gload_lds16(const ushort_t* g, ushort_t* l) {
    __builtin_amdgcn_global_load_lds(
        (const __attribute__((address_space(1))) void*)g,
        (__attribute__((address_space(3))) void*)l,
        16, 0, 0);
}

// ---------------- tiled transpose + convert: in [E][R][C] f32 -> out [E][C][R] bf16 ----
__global__ __launch_bounds__(256) void transpose_conv_kernel(
    const float* __restrict__ in, ushort_t* __restrict__ out, int R, int C)
{
    __shared__ float tile[64][68];
    const int e = blockIdx.z;
    const float* I = in + (size_t)e * R * C;
    ushort_t*    O = out + (size_t)e * R * C;
    const int c0 = blockIdx.x * 64, r0 = blockIdx.y * 64;
    const int tid = threadIdx.x;
#pragma unroll
    for (int j = 0; j < 4; ++j) {
        int row = j * 16 + (tid >> 4);
        int col = (tid & 15) * 4;
        float4 v = *reinterpret_cast<const float4*>(&I[(size_t)(r0 + row) * C + c0 + col]);
        *reinterpret_cast<float4*>(&tile[row][col]) = v;
    }
    __syncthreads();
#pragma unroll
    for (int j = 0; j < 2; ++j) {
        int orow = j * 32 + (tid >> 3);
        int k0   = (tid & 7) * 8;
        uint4 o;
        o.x = pkbf2(tile[k0 + 0][orow], tile[k0 + 1][orow]);
        o.y = pkbf2(tile[k0 + 2][orow], tile[k0 + 3][orow]);
        o.z = pkbf2(tile[k0 + 4][orow], tile[k0 + 5][orow]);
        o.w = pkbf2(tile[k0 + 6][orow], tile[k0 + 7][orow]);
        *reinterpret_cast<uint4*>(&O[(size_t)(c0 + orow) * R + r0 + k0]) = o;
    }
}

// ------- router + x->bf16 convert: 128 blocks x 64 tokens; ballot ranking -------
__global__ __launch_bounds__(256) void router_kernel(
    const float* __restrict__ x, const float* __restrict__ Wr, const float* __restrict__ br,
    int* __restrict__ cnt, int* __restrict__ tok_list, float* __restrict__ w_list,
    ushort_t* __restrict__ xb)
{
    __shared__ int   se0[64], se1[64];
    __shared__ float sw0[64], sw1[64];

    const int wid  = threadIdx.x >> 6;
    const int lane = threadIdx.x & 63;
    const int tblk = blockIdx.x * 64;

    for (int i = 0; i < 16; ++i) {
        const int li = wid * 16 + i;
        const int t  = tblk + li;
        const float* xr = x + (size_t)t * DIM;

        float acc[NE];
#pragma unroll
        for (int e = 0; e < NE; ++e) acc[e] = 0.f;
        for (int d = lane; d < DIM; d += 64) {
            float xv = xr[d];
            const float4* w4 = reinterpret_cast<const float4*>(Wr + (size_t)d * NE);
            float4 w0 = w4[0], w1 = w4[1];
            acc[0] += xv * w0.x; acc[1] += xv * w0.y; acc[2] += xv * w0.z; acc[3] += xv * w0.w;
            acc[4] += xv * w1.x; acc[5] += xv * w1.y; acc[6] += xv * w1.z; acc[7] += xv * w1.w;
        }
#pragma unroll
        for (int e = 0; e < NE; ++e) {
            for (int off = 32; off > 0; off >>= 1)
                acc[e] += __shfl_down(acc[e], off, 64);
        }
        if (lane == 0) {
            float l[NE];
#pragma unroll
            for (int e = 0; e < NE; ++e) l[e] = acc[e] + br[e];
            float mx = l[0];
#pragma unroll
            for (int e = 1; e < NE; ++e) mx = fmaxf(mx, l[e]);
            float p[NE], s = 0.f;
#pragma unroll
            for (int e = 0; e < NE; ++e) { p[e] = expf(l[e] - mx); s += p[e]; }
            float inv = 1.f / s;
            // top-2, lowest-index-on-tie (strict >) to match jax.lax.top_k
            int e0 = 0;
#pragma unroll
            for (int e = 1; e < NE; ++e) if (l[e] > l[e0]) e0 = e;
            int e1 = (e0 == 0) ? 1 : 0;
#pragma unroll
            for (int e = 0; e < NE; ++e) if (e != e0 && l[e] > l[e1]) e1 = e;
            se0[li] = e0; sw0[li] = p[e0] * inv;
            se1[li] = e1; sw1[li] = p[e1] * inv;
        }
    }
    __syncthreads();

    // wave 0: rank 64 tokens x 2 slots per expert, reserve ranges, scatter
    if (threadIdx.x < 64) {
        const int t  = tblk + lane;
        const int e0 = se0[lane], e1 = se1[lane];
        const unsigned long long below = ((unsigned long long)1 << lane) - 1;
        int p0 = 0, p1 = 0;
#pragma unroll
        for (int e = 0; e < NE; ++e) {
            unsigned long long m0 = __ballot(e0 == e);
            unsigned long long m1 = __ballot(e1 == e);
            int c = __popcll(m0) + __popcll(m1);
            int b = 0;
            if (lane == e && c) b = atomicAdd(&cnt[e], c);
            b = __shfl(b, e, 64);
            if (e0 == e) p0 = b + __popcll(m0 & below);
            if (e1 == e) p1 = b + __popcll(m0) + __popcll(m1 & below);
        }
        tok_list[e0 * N_TOK + p0] = t;  w_list[e0 * N_TOK + p0] = sw0[lane];
        tok_list[e1 * N_TOK + p1] = t;  w_list[e1 * N_TOK + p1] = sw1[lane];
    }

    // fused x -> bf16 for this block's 64 tokens (x slice is L2-hot).
    // 64 tok x 1024 dim = 8192 chunks of 8 elems -> 32 iterations x 256 thr.
#pragma unroll
    for (int j = 0; j < 32; ++j) {
        int c  = j * 256 + threadIdx.x;
        int row = c >> 7;
        int d0  = (c & 127) << 3;
        size_t src = ((size_t)(tblk + row) << 10) + d0;
        float4 a = *reinterpret_cast<const float4*>(x + src);
        float4 b = *reinterpret_cast<const float4*>(x + src + 4);
        uint4 o;
        o.x = pkbf2(a.x, a.y); o.y = pkbf2(a.z, a.w);
        o.z = pkbf2(b.x, b.y); o.w = pkbf2(b.z, b.w);
        *reinterpret_cast<uint4*>(xb + src) = o;
    }
}

// scan + live-tile table: tile_e/tile_m0 for every 128-row m-tile (<=136)
__global__ void scan_kernel(const int* __restrict__ cnt, int* __restrict__ offs,
                            int* __restrict__ tile_e, int* __restrict__ tile_m0,
                            int* __restrict__ meta)
{
    if (threadIdx.x == 0 && blockIdx.x == 0) {
        int s = 0;
        for (int e = 0; e < NE; ++e) { offs[e] = s; s += cnt[e]; }
        offs[NE] = s;
        int nt = 0;
        for (int e = 0; e < NE; ++e)
            for (int m0 = 0; m0 < cnt[e]; m0 += 128) {
                tile_e[nt] = e; tile_m0[nt] = m0; ++nt;
            }
        meta[0] = nt;
    }
}

// ------- persistent grouped GEMM, 128x128 tile, BK=32, 8 waves (2x4) -------
// Per-wave 64x32 output. 768 blocks, 3/CU, 24 waves/CU. tau = mt*16 + sub;
// MODE0: sub = nb (16 n-tiles of FF); MODE1: sub = nb*2 + kh (split-K2).
// K-loop: 3 LDS bufs, vmcnt(2);barrier;STAGE(t+2);COMPUTE(t).
// MODE 0: A = xb gathered via tok_list; epilogue bias+GELU staged through LDS
//         (C-tile reuses staging smem) -> coalesced ushort8 h stores.
// MODE 1: A = h (contiguous), epilogue (kh==0?bias:0), * w, atomicAdd -> out
template <int MODE>
__global__ __launch_bounds__(512, 6) void moe_gemm_kernel(
    const ushort_t* __restrict__ A,
    const ushort_t* __restrict__ Bt,    // [NE][NCOL][K] bf16 (K contiguous)
    const float*    __restrict__ bias,  // [NE][NCOL]
    const int*      __restrict__ cnt,
    const int*      __restrict__ offs,
    const int*      __restrict__ tok_list,
    const float*    __restrict__ w_list,
    const int*      __restrict__ tile_e,
    const int*      __restrict__ tile_m0,
    const int*      __restrict__ meta,
    ushort_t*       __restrict__ hout,
    float*          __restrict__ out)
{
    const int K    = (MODE == 0) ? 1024 : 2048;
    const int NCOL = (MODE == 0) ? 2048 : 1024;

    const int nmt = meta[0];
    const int L   = nmt << 4;                 // 16 sub-tiles per m-tile, both modes

    const int xcd = blockIdx.x & 7;
    const int q = L >> 3, r = L & 7;
    const int cstart = (xcd < r) ? xcd * (q + 1) : r * (q + 1) + (xcd - r) * q;
    const int clen   = (xcd < r) ? q + 1 : q;

    // 48 KB: As[b] = smem + b*4096, Bs[b] = smem + 12288 + b*4096.
    // Epilogue (MODE 0) reuses smem[0..16383] as the 128x128 bf16 C tile.
    __shared__ ushort_t smem[24576];
#define ASB(b) (smem + (b) * 4096)
#define BSB(b) (smem + 12288 + (b) * 4096)

    const int tid  = threadIdx.x;
    const int lane = tid & 63;
    const int wid  = tid >> 6;
    const int wr = (wid >> 2) * 64;    // wave rows [wr, wr+64)
    const int wc = (wid & 3) * 32;     // wave cols [wc, wc+32)
    const int la = lane & 15;
    const int kc = lane >> 4;

    for (int i = blockIdx.x >> 3; i < clen; i += 96) {
        const int tau = cstart + i;
        const int mt  = tau >> 4;
        int nb, kh;
        if (MODE == 0) { nb = tau & 15; kh = 0; }
        else           { kh = tau & 1;  nb = (tau >> 1) & 7; }
        const int e   = tile_e[mt];
        const int m0  = tile_m0[mt];
        const int cnt_e  = cnt[e];
        const int offs_e = offs[e];
        const int n0  = nb * 128;
        const int koff = kh << 10;

        __syncthreads();   // prior tile's LDS users done before restaging

        // staging sources: thread c: row=c>>2, chunk=(c&3)^((row>>1)&3); 1 A + 1 B
        const int srow  = tid >> 2;
        const int chunk = (tid & 3) ^ ((srow >> 1) & 3);
        size_t asrc, bsrc;
        {
            int entry = m0 + srow;
            if (MODE == 0) {
                int tok = (entry < cnt_e) ? tok_list[e * N_TOK + entry] : 0;
                asrc = (size_t)tok * K + chunk * 8;
            } else {
                asrc = (size_t)(offs_e + entry) * K + koff + chunk * 8;
            }
            bsrc = ((size_t)e * NCOL + n0 + srow) * K + koff + chunk * 8;
        }

        f32x4 acc[4][2];
#pragma unroll
        for (int m = 0; m < 4; ++m)
#pragma unroll
            for (int n = 0; n < 2; ++n)
                acc[m][n] = (f32x4){0.f, 0.f, 0.f, 0.f};

        auto STAGE = [&](int t, int b) {
            int k0 = t * 32;
            gload_lds16(A  + asrc + k0, ASB(b) + tid * 8);
            gload_lds16(Bt + bsrc + k0, BSB(b) + tid * 8);
        };

        auto COMPUTE = [&](int b) {
            bf16x8 af[4], bfr[2];
#pragma unroll
            for (int m = 0; m < 4; ++m) {
                int rr = wr + m * 16 + la;
                af[m] = *reinterpret_cast<const bf16x8*>(ASB(b) + (rr * 4 + (kc ^ ((rr >> 1) & 3))) * 8);
            }
#pragma unroll
            for (int n = 0; n < 2; ++n) {
                int rr = wc + n * 16 + la;
                bfr[n] = *reinterpret_cast<const bf16x8*>(BSB(b) + (rr * 4 + (kc ^ ((rr >> 1) & 3))) * 8);
            }
            __builtin_amdgcn_s_setprio(1);
#pragma unroll
            for (int m = 0; m < 4; ++m)
#pragma unroll
                for (int n = 0; n < 2; ++n)
                    acc[m][n] = __builtin_amdgcn_mfma_f32_16x16x32_bf16(af[m], bfr[n], acc[m][n], 0, 0, 0);
            __builtin_amdgcn_s_setprio(0);
        };

        const int nk = 32;             // 1024-k window / 32
        STAGE(0, 0);
        STAGE(1, 1);
        for (int t = 0; t < nk - 1; ++t) {
            asm volatile("s_waitcnt vmcnt(2)" ::: "memory");
            __builtin_amdgcn_s_barrier();
            if (t + 2 < nk) STAGE(t + 2, (t + 2) % 3);
            COMPUTE(t % 3);
        }
        asm volatile("s_waitcnt vmcnt(0)" ::: "memory");
        __builtin_amdgcn_s_barrier();
        COMPUTE((nk - 1) % 3);

        // epilogue: C/D layout col = lane&15, row = (lane>>4)*4 + j (HW-verified)
        if (MODE == 0) {
            __syncthreads();           // all waves done with staging smem
#pragma unroll
            for (int m = 0; m < 4; ++m) {
                int rbase = wr + m * 16 + (lane >> 4) * 4;
#pragma unroll
                for (int n = 0; n < 2; ++n) {
                    int ccol = wc + n * 16 + la;
                    float bi = bias[(size_t)e * NCOL + n0 + ccol];
#pragma unroll
                    for (int jj = 0; jj < 4; ++jj) {
                        float v = acc[m][n][jj] + bi;
                        // gelu(tanh approx): tanh(u)=(t2-1)/(t2+1), t2=exp2(2u*log2e)
                        float u = 0.7978845608028654f * (v + 0.044715f * v * v * v);
                        float t2 = __builtin_amdgcn_exp2f(2.8853900817779268f * u);
                        float g = v * (t2 / (t2 + 1.f));
                        smem[(rbase + jj) * 128 + ccol] = f2bf(g);
                    }
                }
            }
            __syncthreads();
#pragma unroll
            for (int j = 0; j < 4; ++j) {
                int c = tid + 512 * j;           // 2048 chunks: row=c>>4, 8 cols
                int row  = c >> 4;
                int col8 = (c & 15) * 8;
                int entry = m0 + row;
                if (entry < cnt_e) {
                    u16x8 v = *reinterpret_cast<const u16x8*>(&smem[row * 128 + col8]);
                    *reinterpret_cast<u16x8*>(&hout[(size_t)(offs_e + entry) * FF + n0 + col8]) = v;
                }
            }
        } else {
#pragma unroll
            for (int m = 0; m < 4; ++m) {
                int rbase = wr + m * 16 + (lane >> 4) * 4;
#pragma unroll
                for (int n = 0; n < 2; ++n) {
                    int gcol = n0 + wc + n * 16 + la;
                    float bi = (kh != 0) ? 0.f : bias[(size_t)e * NCOL + gcol];
#pragma unroll
                    for (int jj = 0; jj < 4; ++jj) {
                        int entry = m0 + rbase + jj;
                        if (entry < cnt_e) {
                            float v = acc[m][n][jj] + bi;
                            int tok  = tok_list[e * N_TOK + entry];
                            float w  = w_list  [e * N_TOK + entry];
                            atomicAdd(&out[(size_t)tok * DIM + gcol], w * v);
                        }
                    }
                }
            }
        }
    }
#undef ASB
#undef BSB
}

extern "C" void kernel_launch(void* const* d_in, const int* in_sizes, int n_in,
                              void* d_out, int out_size, void* d_ws, size_t ws_size,
                              hipStream_t stream)
{
    const float* x  = (const float*)d_in[0];
    const float* Wr = (const float*)d_in[1];
    const float* br = (const float*)d_in[2];
    const float* W1 = (const float*)d_in[3];
    const float* b1 = (const float*)d_in[4];
    const float* W2 = (const float*)d_in[5];
    const float* b2 = (const float*)d_in[6];
    float* out = (float*)d_out;

    // workspace layout (~146 MB total)
    char* ws = (char*)d_ws;
    size_t off = 0;
    auto alloc = [&](size_t bytes) -> void* {
        void* p = ws + off;
        off = (off + bytes + 255) & ~(size_t)255;
        return p;
    };
    ushort_t* w1t = (ushort_t*)alloc((size_t)NE * DIM * FF * 2);          // 32 MB  [E][F][D]
    ushort_t* w2t = (ushort_t*)alloc((size_t)NE * DIM * FF * 2);          // 32 MB  [E][D][F]
    ushort_t* xb  = (ushort_t*)alloc((size_t)N_TOK * DIM * 2);            // 16 MB
    ushort_t* h   = (ushort_t*)alloc(((size_t)2 * N_TOK + 128) * FF * 2); // 64.5 MB (+slack)
    int*      cnt = (int*)alloc(NE * sizeof(int));
    int*      offs= (int*)alloc((NE + 1) * sizeof(int));
    int*   tok_list = (int*)alloc((size_t)NE * N_TOK * sizeof(int));
    float* w_list   = (float*)alloc((size_t)NE * N_TOK * sizeof(float));
    int*   tile_e   = (int*)alloc(256 * sizeof(int));
    int*   tile_m0  = (int*)alloc(256 * sizeof(int));
    int*   meta     = (int*)alloc(16 * sizeof(int));
    (void)ws_size; (void)in_sizes; (void)n_in;

    hipMemsetAsync(out, 0, (size_t)out_size * sizeof(float), stream);
    hipMemsetAsync(cnt, 0, NE * sizeof(int), stream);

    transpose_conv_kernel<<<dim3(FF / 64, DIM / 64, NE), 256, 0, stream>>>(W1, w1t, DIM, FF);
    transpose_conv_kernel<<<dim3(DIM / 64, FF / 64, NE), 256, 0, stream>>>(W2, w2t, FF, DIM);
    router_kernel<<<N_TOK / 64, 256, 0, stream>>>(x, Wr, br, cnt, tok_list, w_list, xb);
    scan_kernel<<<1, 64, 0, stream>>>(cnt, offs, tile_e, tile_m0, meta);

    moe_gemm_kernel<0><<<768, 512, 0, stream>>>(
        xb, w1t, b1, cnt, offs, tok_list, w_list, tile_e, tile_m0, meta, h, nullptr);
    moe_gemm_kernel<1><<<768, 512, 0, stream>>>(
        h, w2t, b2, cnt, offs, tok_list, w_list, tile_e, tile_m0, meta, nullptr, out);
}

// Round 18
// 453.997 us; speedup vs baseline: 1.2881x; 1.0527x over previous
//
#include <hip/hip_runtime.h>
#include <hip/hip_bf16.h>

// MoE top-2 of 8 experts. N=8192 tokens, D=1024, F=2048.
// R18: exact restore of R14 (measured best, 455.6us). R17's router-fused
//      convert regressed (+22us: 128-block grid = 0.5 blocks/CU for the
//      convert sweep); standalone convert_x (4096 blocks, BW-floor) restored.
//      GEMMs: persistent 128x128/BK32/8-wave, 3 LDS bufs, counted
//      vmcnt(2);barrier;STAGE(t+2);COMPUTE(t), mt-major XCD-chunked walk,
//      split-K2 GEMM2, LDS-coalesced GEMM1 epilogue. Stable 186-188us each
//      across 6 rounds; all 13 structural variants measured worse.

#define N_TOK 8192
#define DIM   1024
#define FF    2048
#define NE    8

typedef unsigned short ushort_t;
typedef __bf16 bf16x8 __attribute__((ext_vector_type(8)));
typedef float  f32x4  __attribute__((ext_vector_type(4)));
typedef unsigned short u16x8 __attribute__((ext_vector_type(8)));

__device__ __forceinline__ ushort_t f2bf(float f) {
    union { float f; unsigned int u; } v; v.f = f;
    unsigned int r = (v.u + 0x7FFFu + ((v.u >> 16) & 1u)) >> 16;  // RNE
    return (ushort_t)r;
}

__device__ __forceinline__ unsigned int pkbf2(float lo, float hi) {
    __hip_bfloat162 h = __float22bfloat162_rn(make_float2(lo, hi));
    return *reinterpret_cast<unsigned int*>(&h);
}

__device__ __forceinline__ void gload_lds16(const ushort_t* g, ushort_t* l) {
    __builtin_amdgcn_global_load_lds(
        (const __attribute__((address_space(1))) void*)g,
        (__attribute__((address_space(3))) void*)l,
        16, 0, 0);
}

// ---------------- convert x fp32 -> bf16 (packed) ----------------
__global__ __launch_bounds__(256) void convert_x_kernel(
    const float* __restrict__ x, ushort_t* __restrict__ xb)
{
    size_t i = ((size_t)blockIdx.x * 256 + threadIdx.x) * 8;
    float4 a = *reinterpret_cast<const float4*>(x + i);
    float4 b = *reinterpret_cast<const float4*>(x + i + 4);
    uint4 o;
    o.x = pkbf2(a.x, a.y); o.y = pkbf2(a.z, a.w);
    o.z = pkbf2(b.x, b.y); o.w = pkbf2(b.z, b.w);
    *reinterpret_cast<uint4*>(xb + i) = o;
}

// ---------------- tiled transpose + convert: in [E][R][C] f32 -> out [E][C][R] bf16 ----
__global__ __launch_bounds__(256) void transpose_conv_kernel(
    const float* __restrict__ in, ushort_t* __restrict__ out, int R, int C)
{
    __shared__ float tile[64][68];
    const int e = blockIdx.z;
    const float* I = in + (size_t)e * R * C;
    ushort_t*    O = out + (size_t)e * R * C;
    const int c0 = blockIdx.x * 64, r0 = blockIdx.y * 64;
    const int tid = threadIdx.x;
#pragma unroll
    for (int j = 0; j < 4; ++j) {
        int row = j * 16 + (tid >> 4);
        int col = (tid & 15) * 4;
        float4 v = *reinterpret_cast<const float4*>(&I[(size_t)(r0 + row) * C + c0 + col]);
        *reinterpret_cast<float4*>(&tile[row][col]) = v;
    }
    __syncthreads();
#pragma unroll
    for (int j = 0; j < 2; ++j) {
        int orow = j * 32 + (tid >> 3);
        int k0   = (tid & 7) * 8;
        uint4 o;
        o.x = pkbf2(tile[k0 + 0][orow], tile[k0 + 1][orow]);
        o.y = pkbf2(tile[k0 + 2][orow], tile[k0 + 3][orow]);
        o.z = pkbf2(tile[k0 + 4][orow], tile[k0 + 5][orow]);
        o.w = pkbf2(tile[k0 + 6][orow], tile[k0 + 7][orow]);
        *reinterpret_cast<uint4*>(&O[(size_t)(c0 + orow) * R + r0 + k0]) = o;
    }
}

// ---------------- router: 128 blocks x 64 tokens; ballot ranking, 8 atomics/blk ----
__global__ __launch_bounds__(256) void router_kernel(
    const float* __restrict__ x, const float* __restrict__ Wr, const float* __restrict__ br,
    int* __restrict__ cnt, int* __restrict__ tok_list, float* __restrict__ w_list)
{
    __shared__ int   se0[64], se1[64];
    __shared__ float sw0[64], sw1[64];

    const int wid  = threadIdx.x >> 6;
    const int lane = threadIdx.x & 63;
    const int tblk = blockIdx.x * 64;

    for (int i = 0; i < 16; ++i) {
        const int li = wid * 16 + i;
        const int t  = tblk + li;
        const float* xr = x + (size_t)t * DIM;

        float acc[NE];
#pragma unroll
        for (int e = 0; e < NE; ++e) acc[e] = 0.f;
        for (int d = lane; d < DIM; d += 64) {
            float xv = xr[d];
            const float4* w4 = reinterpret_cast<const float4*>(Wr + (size_t)d * NE);
            float4 w0 = w4[0], w1 = w4[1];
            acc[0] += xv * w0.x; acc[1] += xv * w0.y; acc[2] += xv * w0.z; acc[3] += xv * w0.w;
            acc[4] += xv * w1.x; acc[5] += xv * w1.y; acc[6] += xv * w1.z; acc[7] += xv * w1.w;
        }
#pragma unroll
        for (int e = 0; e < NE; ++e) {
            for (int off = 32; off > 0; off >>= 1)
                acc[e] += __shfl_down(acc[e], off, 64);
        }
        if (lane == 0) {
            float l[NE];
#pragma unroll
            for (int e = 0; e < NE; ++e) l[e] = acc[e] + br[e];
            float mx = l[0];
#pragma unroll
            for (int e = 1; e < NE; ++e) mx = fmaxf(mx, l[e]);
            float p[NE], s = 0.f;
#pragma unroll
            for (int e = 0; e < NE; ++e) { p[e] = expf(l[e] - mx); s += p[e]; }
            float inv = 1.f / s;
            // top-2, lowest-index-on-tie (strict >) to match jax.lax.top_k
            int e0 = 0;
#pragma unroll
            for (int e = 1; e < NE; ++e) if (l[e] > l[e0]) e0 = e;
            int e1 = (e0 == 0) ? 1 : 0;
#pragma unroll
            for (int e = 0; e < NE; ++e) if (e != e0 && l[e] > l[e1]) e1 = e;
            se0[li] = e0; sw0[li] = p[e0] * inv;
            se1[li] = e1; sw1[li] = p[e1] * inv;
        }
    }
    __syncthreads();

    // wave 0: rank 64 tokens x 2 slots per expert, reserve ranges, scatter
    if (threadIdx.x < 64) {
        const int t  = tblk + lane;
        const int e0 = se0[lane], e1 = se1[lane];
        const unsigned long long below = ((unsigned long long)1 << lane) - 1;
        int p0 = 0, p1 = 0;
#pragma unroll
        for (int e = 0; e < NE; ++e) {
            unsigned long long m0 = __ballot(e0 == e);
            unsigned long long m1 = __ballot(e1 == e);
            int c = __popcll(m0) + __popcll(m1);
            int b = 0;
            if (lane == e && c) b = atomicAdd(&cnt[e], c);
            b = __shfl(b, e, 64);
            if (e0 == e) p0 = b + __popcll(m0 & below);
            if (e1 == e) p1 = b + __popcll(m0) + __popcll(m1 & below);
        }
        tok_list[e0 * N_TOK + p0] = t;  w_list[e0 * N_TOK + p0] = sw0[lane];
        tok_list[e1 * N_TOK + p1] = t;  w_list[e1 * N_TOK + p1] = sw1[lane];
    }
}

// scan + live-tile table: tile_e/tile_m0 for every 128-row m-tile (<=136)
__global__ void scan_kernel(const int* __restrict__ cnt, int* __restrict__ offs,
                            int* __restrict__ tile_e, int* __restrict__ tile_m0,
                            int* __restrict__ meta)
{
    if (threadIdx.x == 0 && blockIdx.x == 0) {
        int s = 0;
        for (int e = 0; e < NE; ++e) { offs[e] = s; s += cnt[e]; }
        offs[NE] = s;
        int nt = 0;
        for (int e = 0; e < NE; ++e)
            for (int m0 = 0; m0 < cnt[e]; m0 += 128) {
                tile_e[nt] = e; tile_m0[nt] = m0; ++nt;
            }
        meta[0] = nt;
    }
}

// ------- persistent grouped GEMM, 128x128 tile, BK=32, 8 waves (2x4) -------
// Per-wave 64x32 output. 768 blocks, 3/CU, 24 waves/CU. tau = mt*16 + sub;
// MODE0: sub = nb (16 n-tiles of FF); MODE1: sub = nb*2 + kh (split-K2).
// K-loop: 3 LDS bufs, vmcnt(2);barrier;STAGE(t+2);COMPUTE(t).
// MODE 0: A = xb gathered via tok_list; epilogue bias+GELU staged through LDS
//         (C-tile reuses staging smem) -> coalesced ushort8 h stores.
// MODE 1: A = h (contiguous), epilogue (kh==0?bias:0), * w, atomicAdd -> out
template <int MODE>
__global__ __launch_bounds__(512, 6) void moe_gemm_kernel(
    const ushort_t* __restrict__ A,
    const ushort_t* __restrict__ Bt,    // [NE][NCOL][K] bf16 (K contiguous)
    const float*    __restrict__ bias,  // [NE][NCOL]
    const int*      __restrict__ cnt,
    const int*      __restrict__ offs,
    const int*      __restrict__ tok_list,
    const float*    __restrict__ w_list,
    const int*      __restrict__ tile_e,
    const int*      __restrict__ tile_m0,
    const int*      __restrict__ meta,
    ushort_t*       __restrict__ hout,
    float*          __restrict__ out)
{
    const int K    = (MODE == 0) ? 1024 : 2048;
    const int NCOL = (MODE == 0) ? 2048 : 1024;

    const int nmt = meta[0];
    const int L   = nmt << 4;                 // 16 sub-tiles per m-tile, both modes

    const int xcd = blockIdx.x & 7;
    const int q = L >> 3, r = L & 7;
    const int cstart = (xcd < r) ? xcd * (q + 1) : r * (q + 1) + (xcd - r) * q;
    const int clen   = (xcd < r) ? q + 1 : q;

    // 48 KB: As[b] = smem + b*4096, Bs[b] = smem + 12288 + b*4096.
    // Epilogue (MODE 0) reuses smem[0..16383] as the 128x128 bf16 C tile.
    __shared__ ushort_t smem[24576];
#define ASB(b) (smem + (b) * 4096)
#define BSB(b) (smem + 12288 + (b) * 4096)

    const int tid  = threadIdx.x;
    const int lane = tid & 63;
    const int wid  = tid >> 6;
    const int wr = (wid >> 2) * 64;    // wave rows [wr, wr+64)
    const int wc = (wid & 3) * 32;     // wave cols [wc, wc+32)
    const int la = lane & 15;
    const int kc = lane >> 4;

    for (int i = blockIdx.x >> 3; i < clen; i += 96) {
        const int tau = cstart + i;
        const int mt  = tau >> 4;
        int nb, kh;
        if (MODE == 0) { nb = tau & 15; kh = 0; }
        else           { kh = tau & 1;  nb = (tau >> 1) & 7; }
        const int e   = tile_e[mt];
        const int m0  = tile_m0[mt];
        const int cnt_e  = cnt[e];
        const int offs_e = offs[e];
        const int n0  = nb * 128;
        const int koff = kh << 10;

        __syncthreads();   // prior tile's LDS users done before restaging

        // staging sources: thread c: row=c>>2, chunk=(c&3)^((row>>1)&3); 1 A + 1 B
        const int srow  = tid >> 2;
        const int chunk = (tid & 3) ^ ((srow >> 1) & 3);
        size_t asrc, bsrc;
        {
            int entry = m0 + srow;
            if (MODE == 0) {
                int tok = (entry < cnt_e) ? tok_list[e * N_TOK + entry] : 0;
                asrc = (size_t)tok * K + chunk * 8;
            } else {
                asrc = (size_t)(offs_e + entry) * K + koff + chunk * 8;
            }
            bsrc = ((size_t)e * NCOL + n0 + srow) * K + koff + chunk * 8;
        }

        f32x4 acc[4][2];
#pragma unroll
        for (int m = 0; m < 4; ++m)
#pragma unroll
            for (int n = 0; n < 2; ++n)
                acc[m][n] = (f32x4){0.f, 0.f, 0.f, 0.f};

        auto STAGE = [&](int t, int b) {
            int k0 = t * 32;
            gload_lds16(A  + asrc + k0, ASB(b) + tid * 8);
            gload_lds16(Bt + bsrc + k0, BSB(b) + tid * 8);
        };

        auto COMPUTE = [&](int b) {
            bf16x8 af[4], bfr[2];
#pragma unroll
            for (int m = 0; m < 4; ++m) {
                int rr = wr + m * 16 + la;
                af[m] = *reinterpret_cast<const bf16x8*>(ASB(b) + (rr * 4 + (kc ^ ((rr >> 1) & 3))) * 8);
            }
#pragma unroll
            for (int n = 0; n < 2; ++n) {
                int rr = wc + n * 16 + la;
                bfr[n] = *reinterpret_cast<const bf16x8*>(BSB(b) + (rr * 4 + (kc ^ ((rr >> 1) & 3))) * 8);
            }
            __builtin_amdgcn_s_setprio(1);
#pragma unroll
            for (int m = 0; m < 4; ++m)
#pragma unroll
                for (int n = 0; n < 2; ++n)
                    acc[m][n] = __builtin_amdgcn_mfma_f32_16x16x32_bf16(af[m], bfr[n], acc[m][n], 0, 0, 0);
            __builtin_amdgcn_s_setprio(0);
        };

        const int nk = 32;             // 1024-k window / 32
        STAGE(0, 0);
        STAGE(1, 1);
        for (int t = 0; t < nk - 1; ++t) {
            asm volatile("s_waitcnt vmcnt(2)" ::: "memory");
            __builtin_amdgcn_s_barrier();
            if (t + 2 < nk) STAGE(t + 2, (t + 2) % 3);
            COMPUTE(t % 3);
        }
        asm volatile("s_waitcnt vmcnt(0)" ::: "memory");
        __builtin_amdgcn_s_barrier();
        COMPUTE((nk - 1) % 3);

        // epilogue: C/D layout col = lane&15, row = (lane>>4)*4 + j (HW-verified)
        if (MODE == 0) {
            __syncthreads();           // all waves done with staging smem
#pragma unroll
            for (int m = 0; m < 4; ++m) {
                int rbase = wr + m * 16 + (lane >> 4) * 4;
#pragma unroll
                for (int n = 0; n < 2; ++n) {
                    int ccol = wc + n * 16 + la;
                    float bi = bias[(size_t)e * NCOL + n0 + ccol];
#pragma unroll
                    for (int jj = 0; jj < 4; ++jj) {
                        float v = acc[m][n][jj] + bi;
                        // gelu(tanh approx): tanh(u)=(t2-1)/(t2+1), t2=exp2(2u*log2e)
                        float u = 0.7978845608028654f * (v + 0.044715f * v * v * v);
                        float t2 = __builtin_amdgcn_exp2f(2.8853900817779268f * u);
                        float g = v * (t2 / (t2 + 1.f));
                        smem[(rbase + jj) * 128 + ccol] = f2bf(g);
                    }
                }
            }
            __syncthreads();
#pragma unroll
            for (int j = 0; j < 4; ++j) {
                int c = tid + 512 * j;           // 2048 chunks: row=c>>4, 8 cols
                int row  = c >> 4;
                int col8 = (c & 15) * 8;
                int entry = m0 + row;
                if (entry < cnt_e) {
                    u16x8 v = *reinterpret_cast<const u16x8*>(&smem[row * 128 + col8]);
                    *reinterpret_cast<u16x8*>(&hout[(size_t)(offs_e + entry) * FF + n0 + col8]) = v;
                }
            }
        } else {
#pragma unroll
            for (int m = 0; m < 4; ++m) {
                int rbase = wr + m * 16 + (lane >> 4) * 4;
#pragma unroll
                for (int n = 0; n < 2; ++n) {
                    int gcol = n0 + wc + n * 16 + la;
                    float bi = (kh != 0) ? 0.f : bias[(size_t)e * NCOL + gcol];
#pragma unroll
                    for (int jj = 0; jj < 4; ++jj) {
                        int entry = m0 + rbase + jj;
                        if (entry < cnt_e) {
                            float v = acc[m][n][jj] + bi;
                            int tok  = tok_list[e * N_TOK + entry];
                            float w  = w_list  [e * N_TOK + entry];
                            atomicAdd(&out[(size_t)tok * DIM + gcol], w * v);
                        }
                    }
                }
            }
        }
    }
#undef ASB
#undef BSB
}

extern "C" void kernel_launch(void* const* d_in, const int* in_sizes, int n_in,
                              void* d_out, int out_size, void* d_ws, size_t ws_size,
                              hipStream_t stream)
{
    const float* x  = (const float*)d_in[0];
    const float* Wr = (const float*)d_in[1];
    const float* br = (const float*)d_in[2];
    const float* W1 = (const float*)d_in[3];
    const float* b1 = (const float*)d_in[4];
    const float* W2 = (const float*)d_in[5];
    const float* b2 = (const float*)d_in[6];
    float* out = (float*)d_out;

    // workspace layout (~146 MB total)
    char* ws = (char*)d_ws;
    size_t off = 0;
    auto alloc = [&](size_t bytes) -> void* {
        void* p = ws + off;
        off = (off + bytes + 255) & ~(size_t)255;
        return p;
    };
    ushort_t* w1t = (ushort_t*)alloc((size_t)NE * DIM * FF * 2);          // 32 MB  [E][F][D]
    ushort_t* w2t = (ushort_t*)alloc((size_t)NE * DIM * FF * 2);          // 32 MB  [E][D][F]
    ushort_t* xb  = (ushort_t*)alloc((size_t)N_TOK * DIM * 2);            // 16 MB
    ushort_t* h   = (ushort_t*)alloc(((size_t)2 * N_TOK + 128) * FF * 2); // 64.5 MB (+slack)
    int*      cnt = (int*)alloc(NE * sizeof(int));
    int*      offs= (int*)alloc((NE + 1) * sizeof(int));
    int*   tok_list = (int*)alloc((size_t)NE * N_TOK * sizeof(int));
    float* w_list   = (float*)alloc((size_t)NE * N_TOK * sizeof(float));
    int*   tile_e   = (int*)alloc(256 * sizeof(int));
    int*   tile_m0  = (int*)alloc(256 * sizeof(int));
    int*   meta     = (int*)alloc(16 * sizeof(int));
    (void)ws_size; (void)in_sizes; (void)n_in;

    hipMemsetAsync(out, 0, (size_t)out_size * sizeof(float), stream);
    hipMemsetAsync(cnt, 0, NE * sizeof(int), stream);

    convert_x_kernel<<<(N_TOK * DIM) / (8 * 256), 256, 0, stream>>>(x, xb);
    transpose_conv_kernel<<<dim3(FF / 64, DIM / 64, NE), 256, 0, stream>>>(W1, w1t, DIM, FF);
    transpose_conv_kernel<<<dim3(DIM / 64, FF / 64, NE), 256, 0, stream>>>(W2, w2t, FF, DIM);
    router_kernel<<<N_TOK / 64, 256, 0, stream>>>(x, Wr, br, cnt, tok_list, w_list);
    scan_kernel<<<1, 64, 0, stream>>>(cnt, offs, tile_e, tile_m0, meta);

    moe_gemm_kernel<0><<<768, 512, 0, stream>>>(
        xb, w1t, b1, cnt, offs, tok_list, w_list, tile_e, tile_m0, meta, h, nullptr);
    moe_gemm_kernel<1><<<768, 512, 0, stream>>>(
        h, w2t, b2, cnt, offs, tok_list, w_list, tile_e, tile_m0, meta, nullptr, out);
}